// Round 1
// baseline (209.836 us; speedup 1.0000x reference)
//
#include <hip/hip_runtime.h>
#include <math.h>

#define NN 4096
#define IN_DIM 256
#define HEADS 4
#define OUT_DIM 64

__device__ __forceinline__ float fexp(float x){ return __expf(x); }

// ---------------- K1: Wh = h @ W  (f32, LDS-staged, 16-row tiles) ----------------
__global__ void k_gemm(const float* __restrict__ h, const float* __restrict__ W,
                       float* __restrict__ Wh){
    __shared__ float hs[IN_DIM][17];      // hs[k][r] : h[i0+r][k], padded (bank-conflict-free writes)
    const int i0 = blockIdx.x * 16;
    const int t  = threadIdx.x;           // 256 threads = output column
    #pragma unroll
    for (int r = 0; r < 16; ++r) hs[t][r] = h[(i0 + r) * IN_DIM + t];
    __syncthreads();
    float acc[16];
    #pragma unroll
    for (int r = 0; r < 16; ++r) acc[r] = 0.f;
    for (int k = 0; k < IN_DIM; ++k) {
        float w = W[k * 256 + t];
        #pragma unroll
        for (int r = 0; r < 16; ++r) acc[r] += hs[k][r] * w;
    }
    #pragma unroll
    for (int r = 0; r < 16; ++r) Wh[(i0 + r) * 256 + t] = acc[r];
}

// ---------------- K2: f_i[n,h], f_j[n,h] = dot(Wh[n,h,:], a[h, :64 / 64:]) ----------------
__global__ void k_fvec(const float* __restrict__ Wh, const float* __restrict__ a,
                       float* __restrict__ fi, float* __restrict__ fj){
    const int n = blockIdx.x;
    const int t = threadIdx.x;            // 256 = 4 waves, wave = head
    const int hh = t >> 6, d = t & 63;
    float v  = Wh[n * 256 + hh * 64 + d];
    float p1 = v * a[hh * 128 + d];
    float p2 = v * a[hh * 128 + 64 + d];
    #pragma unroll
    for (int off = 32; off; off >>= 1) {
        p1 += __shfl_down(p1, off);
        p2 += __shfl_down(p2, off);
    }
    if (d == 0) { fi[n * 4 + hh] = p1; fj[n * 4 + hh] = p2; }
}

// ---------------- K3: rank-sort f_j per head (counting rank, ties by index) ----------------
__global__ void k_rank(const float* __restrict__ fj, float* __restrict__ fs,
                       int* __restrict__ js){
    const int j0 = blockIdx.x * 8;        // 8 nodes per block
    const int t = threadIdx.x;
    const int hh = t >> 6, d = t & 63;    // wave = head
    float v[8]; int cnt[8];
    #pragma unroll
    for (int r = 0; r < 8; ++r) { v[r] = fj[(j0 + r) * 4 + hh]; cnt[r] = 0; }
    for (int m = 0; m < 64; ++m) {
        int jp = d + m * 64;
        float x = fj[jp * 4 + hh];
        #pragma unroll
        for (int r = 0; r < 8; ++r)
            cnt[r] += (x < v[r] || (x == v[r] && jp < (j0 + r))) ? 1 : 0;
    }
    #pragma unroll
    for (int r = 0; r < 8; ++r)
        for (int off = 32; off; off >>= 1) cnt[r] += __shfl_down(cnt[r], off);
    if (d == 0) {
        #pragma unroll
        for (int r = 0; r < 8; ++r) { fs[hh * NN + cnt[r]] = v[r]; js[hh * NN + cnt[r]] = j0 + r; }
    }
}

// ---------------- K4: per-chunk sums of exp(fs)*Wh and exp(0.2fs)*Wh ----------------
__global__ void k_chunks(const float* __restrict__ fs, const int* __restrict__ js,
                         const float* __restrict__ Wh,
                         float* __restrict__ cs1, float* __restrict__ cs2,
                         float* __restrict__ cz1, float* __restrict__ cz2){
    const int b = blockIdx.x;             // 4 heads * 64 chunks
    const int hh = b >> 6, c = b & 63;
    const int d = threadIdx.x;            // 64 threads = out dim
    float a1 = 0.f, a2 = 0.f, z1 = 0.f, z2 = 0.f;
    for (int q = c * 64; q < c * 64 + 64; ++q) {
        float f = fs[hh * NN + q];
        int jr  = js[hh * NN + q];
        float e1 = fexp(f), e2 = fexp(0.2f * f);
        float wv = Wh[jr * 256 + hh * 64 + d];
        a1 += e1 * wv; a2 += e2 * wv; z1 += e1; z2 += e2;
    }
    cs1[(hh * 64 + c) * 64 + d] = a1;
    cs2[(hh * 64 + c) * 64 + d] = a2;
    if (d == 0) { cz1[hh * 64 + c] = z1; cz2[hh * 64 + c] = z2; }
}

// ---------------- K5: chunk-level suffix(S1)/prefix(S2) scans ----------------
__global__ void k_scan(const float* __restrict__ cs1, const float* __restrict__ cs2,
                       const float* __restrict__ cz1, const float* __restrict__ cz2,
                       float* __restrict__ S1, float* __restrict__ S2,
                       float* __restrict__ Z1, float* __restrict__ Z2){
    const int t = threadIdx.x;            // 256 = 4 heads * 64 d
    const int hh = t >> 6, d = t & 63;
    float acc = 0.f;
    S1[(hh * 65 + 64) * 64 + d] = 0.f;
    for (int c = 63; c >= 0; --c) { acc += cs1[(hh * 64 + c) * 64 + d]; S1[(hh * 65 + c) * 64 + d] = acc; }
    acc = 0.f;
    S2[(hh * 65 + 0) * 64 + d] = 0.f;
    for (int c = 0; c < 64; ++c) { acc += cs2[(hh * 64 + c) * 64 + d]; S2[(hh * 65 + c + 1) * 64 + d] = acc; }
    if (d == 0) {
        float az = 0.f; Z1[hh * 65 + 64] = 0.f;
        for (int c = 63; c >= 0; --c) { az += cz1[hh * 64 + c]; Z1[hh * 65 + c] = az; }
        az = 0.f; Z2[hh * 65 + 0] = 0.f;
        for (int c = 0; c < 64; ++c) { az += cz2[hh * 64 + c]; Z2[hh * 65 + c + 1] = az; }
    }
}

// ---------------- K6: per-(i,h) query: out row + invZ ----------------
__global__ void k_query(const float* __restrict__ fi, const float* __restrict__ fs,
                        const int* __restrict__ js, const float* __restrict__ Wh,
                        const float* __restrict__ S1, const float* __restrict__ S2,
                        const float* __restrict__ Z1, const float* __restrict__ Z2,
                        float* __restrict__ out, float* __restrict__ invZ){
    const int i = blockIdx.x;
    const int t = threadIdx.x;            // 256 = 4 waves, wave = head
    const int hh = t >> 6, d = t & 63;
    const float s = fi[i * 4 + hh];
    const float thr = -s;
    const float* fsh = fs + hh * NN;
    // p = #{q : fs[q] < thr}  (== lower_bound since fs sorted ascending)
    int cnt = 0;
    for (int m = 0; m < 64; ++m) cnt += (fsh[d + m * 64] < thr) ? 1 : 0;
    #pragma unroll
    for (int off = 32; off; off >>= 1) cnt += __shfl_down(cnt, off);
    const int p = __shfl(cnt, 0);
    const int c = min(p >> 6, 63);
    // within-chunk partials split at p
    float a1 = 0.f, a2 = 0.f, z1 = 0.f, z2 = 0.f;
    for (int q = c * 64; q < c * 64 + 64; ++q) {
        float f = fsh[q];
        int jr  = js[hh * NN + q];
        float wv = Wh[jr * 256 + hh * 64 + d];
        if (q >= p) { float e = fexp(f);        a1 += e * wv; z1 += e; }
        else        { float e = fexp(0.2f * f); a2 += e * wv; z2 += e; }
    }
    a1 += S1[(hh * 65 + c + 1) * 64 + d];
    a2 += S2[(hh * 65 + c) * 64 + d];
    z1 += Z1[hh * 65 + c + 1];
    z2 += Z2[hh * 65 + c];
    const float E1 = fexp(s), E2 = fexp(0.2f * s);
    const float Zt = E1 * z1 + E2 * z2;
    const float iz = 1.f / Zt;
    out[i * 256 + hh * 64 + d] = (E1 * a1 + E2 * a2) * iz;
    if (d == 0) invZ[i * 4 + hh] = iz;
}

// ---------------- K7: attn[i,j,h] = exp(lrelu(f_i+f_j)) * invZ  (float4 stores) ----------------
__global__ void k_attn(const float4* __restrict__ fi4, const float4* __restrict__ fj4,
                       const float4* __restrict__ iz4, float4* __restrict__ attn){
    const long long total  = (long long)NN * NN;      // 16.7M float4
    const long long stride = (long long)gridDim.x * blockDim.x;
    for (long long u = (long long)blockIdx.x * blockDim.x + threadIdx.x; u < total; u += stride) {
        const int i = (int)(u >> 12);
        const int j = (int)(u & 4095);
        const float4 fiv = fi4[i];
        const float4 fjv = fj4[j];
        const float4 izv = iz4[i];
        float4 o;
        float x;
        x = fiv.x + fjv.x; x = fmaxf(x, 0.2f * x); o.x = fexp(x) * izv.x;
        x = fiv.y + fjv.y; x = fmaxf(x, 0.2f * x); o.y = fexp(x) * izv.y;
        x = fiv.z + fjv.z; x = fmaxf(x, 0.2f * x); o.z = fexp(x) * izv.z;
        x = fiv.w + fjv.w; x = fmaxf(x, 0.2f * x); o.w = fexp(x) * izv.w;
        attn[u] = o;
    }
}

extern "C" void kernel_launch(void* const* d_in, const int* in_sizes, int n_in,
                              void* d_out, int out_size, void* d_ws, size_t ws_size,
                              hipStream_t stream) {
    const float* h = (const float*)d_in[0];
    const float* W = (const float*)d_in[1];
    const float* a = (const float*)d_in[2];
    float* out = (float*)d_out;
    float* ws  = (float*)d_ws;

    float* Wh   = ws;                 // 1,048,576
    float* fi   = Wh  + 1048576;      // 16,384
    float* fj   = fi  + 16384;        // 16,384
    float* invZ = fj  + 16384;        // 16,384
    float* fs   = invZ + 16384;       // 16,384
    int*   js   = (int*)(fs + 16384); // 16,384 ints
    float* cs1  = (float*)(js + 16384); // 16,384
    float* cs2  = cs1 + 16384;        // 16,384
    float* cz1  = cs2 + 16384;        // 256
    float* cz2  = cz1 + 256;          // 256
    float* S1   = cz2 + 256;          // 16,640
    float* S2   = S1  + 16640;        // 16,640
    float* Z1   = S2  + 16640;        // 260
    float* Z2   = Z1  + 260;          // 260

    k_gemm  <<<NN / 16, 256, 0, stream>>>(h, W, Wh);
    k_fvec  <<<NN, 256, 0, stream>>>(Wh, a, fi, fj);
    k_rank  <<<NN / 8, 256, 0, stream>>>(fj, fs, js);
    k_chunks<<<HEADS * 64, 64, 0, stream>>>(fs, js, Wh, cs1, cs2, cz1, cz2);
    k_scan  <<<1, 256, 0, stream>>>(cs1, cs2, cz1, cz2, S1, S2, Z1, Z2);
    k_query <<<NN, 256, 0, stream>>>(fi, fs, js, Wh, S1, S2, Z1, Z2, out, invZ);

    float* attn = out + (NN * HEADS * OUT_DIM);   // 1,048,576 offset
    k_attn  <<<4096, 256, 0, stream>>>((const float4*)fi, (const float4*)fj,
                                       (const float4*)invZ, (float4*)attn);
}

// Round 2
// 158.202 us; speedup vs baseline: 1.3264x; 1.3264x over previous
//
#include <hip/hip_runtime.h>
#include <math.h>

#define NN 4096
#define IN_DIM 256
#define HEADS 4
#define OUT_DIM 64

__device__ __forceinline__ float fexp(float x){ return __expf(x); }

// ---- K1: Wh = h@W fused with f_i/f_j/exp(f_j) tables ----
__global__ void k_gw(const float* __restrict__ h, const float* __restrict__ W,
                     const float* __restrict__ a,
                     float* __restrict__ Wh, float* __restrict__ fi, float* __restrict__ fj,
                     float* __restrict__ E1j, float* __restrict__ E2j){
    __shared__ float hs[IN_DIM][17];
    const int i0 = blockIdx.x * 16;
    const int t  = threadIdx.x;           // output column
    const int hh = t >> 6, d = t & 63;    // wave == head
    #pragma unroll
    for (int r = 0; r < 16; ++r) hs[t][r] = h[(i0 + r) * IN_DIM + t];
    __syncthreads();
    float acc[16];
    #pragma unroll
    for (int r = 0; r < 16; ++r) acc[r] = 0.f;
    for (int k = 0; k < IN_DIM; ++k) {
        float w = W[k * 256 + t];
        #pragma unroll
        for (int r = 0; r < 16; ++r) acc[r] += hs[k][r] * w;
    }
    const float aD = a[hh * 128 + d];
    const float aS = a[hh * 128 + 64 + d];
    #pragma unroll
    for (int r = 0; r < 16; ++r) {
        Wh[(i0 + r) * 256 + t] = acc[r];
        float p1 = acc[r] * aD, p2 = acc[r] * aS;
        #pragma unroll
        for (int off = 32; off; off >>= 1) {
            p1 += __shfl_down(p1, off);
            p2 += __shfl_down(p2, off);
        }
        if (d == 0) {
            const int n = i0 + r;
            fi[n * 4 + hh]  = p1;
            fj[n * 4 + hh]  = p2;
            E1j[n * 4 + hh] = fexp(p2);
            E2j[n * 4 + hh] = fexp(0.2f * p2);
        }
    }
}

// ---- K2: rank f_j per head (counting rank, index tiebreak) + permute Wh into sorted order ----
__global__ void k_rp(const float* __restrict__ fj, const float* __restrict__ Wh,
                     float* __restrict__ fs, float* __restrict__ Whp){
    const int j0 = blockIdx.x * 8;
    const int t = threadIdx.x;
    const int hh = t >> 6, d = t & 63;    // wave == head
    float v[8]; int cnt[8];
    #pragma unroll
    for (int r = 0; r < 8; ++r) { v[r] = fj[(j0 + r) * 4 + hh]; cnt[r] = 0; }
    for (int m = 0; m < 64; ++m) {
        const int jp = d + m * 64;
        const float x = fj[jp * 4 + hh];
        #pragma unroll
        for (int r = 0; r < 8; ++r)
            cnt[r] += (x < v[r] || (x == v[r] && jp < (j0 + r))) ? 1 : 0;
    }
    #pragma unroll
    for (int r = 0; r < 8; ++r) {
        int c = cnt[r];
        #pragma unroll
        for (int off = 32; off; off >>= 1) c += __shfl_down(c, off);
        const int rank = __shfl(c, 0);
        if (d == 0) fs[hh * NN + rank] = v[r];
        Whp[(hh * NN + rank) * 64 + d] = Wh[(j0 + r) * 256 + hh * 64 + d];
    }
}

// ---- K3: per-chunk fine suffix/prefix sums + chunk totals ----
__global__ void k_chunks(const float* __restrict__ fs, const float* __restrict__ Whp,
                         float* __restrict__ r1, float* __restrict__ r2x,
                         float* __restrict__ rz1, float* __restrict__ rz2x,
                         float* __restrict__ cs1, float* __restrict__ cs2,
                         float* __restrict__ cz1, float* __restrict__ cz2){
    const int b = blockIdx.x;             // 4 heads * 64 chunks
    const int H = b >> 6, c = b & 63;
    const int d = threadIdx.x;
    const int base = H * NN, q0 = c * 64;
    float a2 = 0.f, z2 = 0.f;
    #pragma unroll 4
    for (int q = q0; q < q0 + 64; ++q) {
        const float f  = fs[base + q];
        const float e2 = fexp(0.2f * f);
        const float wv = Whp[(base + q) * 64 + d];
        r2x[(base + q) * 64 + d] = a2;            // exclusive prefix
        if (d == 0) rz2x[base + q] = z2;
        a2 += e2 * wv; z2 += e2;
    }
    float a1 = 0.f, z1 = 0.f;
    #pragma unroll 4
    for (int q = q0 + 63; q >= q0; --q) {
        const float f  = fs[base + q];
        const float e1 = fexp(f);
        const float wv = Whp[(base + q) * 64 + d];
        a1 += e1 * wv; z1 += e1;
        r1[(base + q) * 64 + d] = a1;             // inclusive suffix
        if (d == 0) rz1[base + q] = z1;
    }
    cs1[b * 64 + d] = a1;
    cs2[b * 64 + d] = a2;
    if (d == 0) { cz1[b] = z1; cz2[b] = z2; }
}

// ---- K4: chunk-level scans (one block per head) ----
__global__ void k_scan(const float* __restrict__ cs1, const float* __restrict__ cs2,
                       const float* __restrict__ cz1, const float* __restrict__ cz2,
                       float* __restrict__ S1, float* __restrict__ S2,
                       float* __restrict__ Z1, float* __restrict__ Z2){
    const int H = blockIdx.x;
    const int t = threadIdx.x;
    if (t < 64) {
        const int d = t; float acc = 0.f;
        S1[(H * 65 + 64) * 64 + d] = 0.f;
        #pragma unroll 8
        for (int c = 63; c >= 0; --c) { acc += cs1[(H * 64 + c) * 64 + d]; S1[(H * 65 + c) * 64 + d] = acc; }
    } else if (t < 128) {
        const int d = t - 64; float acc = 0.f;
        S2[(H * 65 + 0) * 64 + d] = 0.f;
        #pragma unroll 8
        for (int c = 0; c < 64; ++c) { acc += cs2[(H * 64 + c) * 64 + d]; S2[(H * 65 + c + 1) * 64 + d] = acc; }
    } else if (t == 128) {
        float acc = 0.f; Z1[H * 65 + 64] = 0.f;
        for (int c = 63; c >= 0; --c) { acc += cz1[H * 64 + c]; Z1[H * 65 + c] = acc; }
    } else if (t == 129) {
        float acc = 0.f; Z2[H * 65 + 0] = 0.f;
        for (int c = 0; c < 64; ++c) { acc += cz2[H * 64 + c]; Z2[H * 65 + c + 1] = acc; }
    }
}

// ---- K5: query — ballot-based position search + O(1) loads ----
__global__ void k_q(const float* __restrict__ fi, const float* __restrict__ fs,
                    const float* __restrict__ r1, const float* __restrict__ r2x,
                    const float* __restrict__ rz1, const float* __restrict__ rz2x,
                    const float* __restrict__ S1, const float* __restrict__ S2,
                    const float* __restrict__ Z1, const float* __restrict__ Z2,
                    float* __restrict__ out, float* __restrict__ thrE,
                    float* __restrict__ A1, float* __restrict__ A2){
    const int i = blockIdx.x;
    const int t = threadIdx.x;
    const int hh = t >> 6, d = t & 63;    // wave == head
    const int base = hh * NN;
    const float s = fi[i * 4 + hh];
    const float thr = -s;
    // p = #{q : fs[q] < thr} via 64-ary search (2 ballots)
    const unsigned long long m1 = __ballot(fs[base + d * 64] < thr);
    const int k1 = __popcll(m1);
    int p = 0;
    if (k1 > 0) {
        const int cc = k1 - 1;
        const unsigned long long m2 = __ballot(fs[base + cc * 64 + d] < thr);
        p = cc * 64 + __popcll(m2);
    }
    float a1, a2, z1, z2;
    if (p == NN) {
        a1 = 0.f; z1 = 0.f;
        a2 = S2[(hh * 65 + 64) * 64 + d]; z2 = Z2[hh * 65 + 64];
    } else {
        const int c = p >> 6;
        a1 = r1 [(base + p) * 64 + d] + S1[(hh * 65 + c + 1) * 64 + d];
        z1 = rz1[base + p]            + Z1[hh * 65 + c + 1];
        a2 = r2x[(base + p) * 64 + d] + S2[(hh * 65 + c) * 64 + d];
        z2 = rz2x[base + p]           + Z2[hh * 65 + c];
    }
    const float E1 = fexp(s), E2 = fexp(0.2f * s);
    const float iz = 1.f / (E1 * z1 + E2 * z2);
    out[i * 256 + t] = (E1 * a1 + E2 * a2) * iz;
    if (d == 0) {
        thrE[i * 4 + hh] = fexp(thr);
        A1[i * 4 + hh]   = E1 * iz;
        A2[i * 4 + hh]   = E2 * iz;
    }
}

// ---- K6: attn write — no transcendentals, 2 table loads + select per quad ----
__global__ void k_attn(const float4* __restrict__ E1j4, const float4* __restrict__ E2j4,
                       const float4* __restrict__ thrE4, const float4* __restrict__ A14,
                       const float4* __restrict__ A24, float4* __restrict__ attn){
    const int i = blockIdx.x;
    const float4 th = thrE4[i];
    const float4 a1 = A14[i];
    const float4 a2 = A24[i];
    float4* __restrict__ row = attn + (size_t)i * NN;
    const int t = threadIdx.x;
    #pragma unroll
    for (int it = 0; it < 16; ++it) {
        const int j = it * 256 + t;
        const float4 e1 = E1j4[j];
        const float4 e2 = E2j4[j];
        float4 o;
        o.x = (e1.x >= th.x) ? a1.x * e1.x : a2.x * e2.x;
        o.y = (e1.y >= th.y) ? a1.y * e1.y : a2.y * e2.y;
        o.z = (e1.z >= th.z) ? a1.z * e1.z : a2.z * e2.z;
        o.w = (e1.w >= th.w) ? a1.w * e1.w : a2.w * e2.w;
        row[j] = o;
    }
}

extern "C" void kernel_launch(void* const* d_in, const int* in_sizes, int n_in,
                              void* d_out, int out_size, void* d_ws, size_t ws_size,
                              hipStream_t stream) {
    const float* h = (const float*)d_in[0];
    const float* W = (const float*)d_in[1];
    const float* a = (const float*)d_in[2];
    float* out = (float*)d_out;
    float* ws  = (float*)d_ws;

    float* Wh   = ws;                   // 1,048,576
    float* Whp  = Wh   + 1048576;       // 1,048,576
    float* fi   = Whp  + 1048576;       // 16,384
    float* fj   = fi   + 16384;         // 16,384
    float* E1j  = fj   + 16384;         // 16,384
    float* E2j  = E1j  + 16384;         // 16,384
    float* fs   = E2j  + 16384;         // 16,384
    float* cs1  = fs   + 16384;         // 16,384
    float* cs2  = cs1  + 16384;         // 16,384
    float* cz1  = cs2  + 16384;         // 256
    float* cz2  = cz1  + 256;           // 256
    float* S1   = cz2  + 256;           // 16,640
    float* S2   = S1   + 16640;         // 16,640
    float* Z1   = S2   + 16640;         // 260
    float* Z2   = Z1   + 260;           // 260
    float* r1   = Z2   + 260;           // 1,048,576
    float* r2x  = r1   + 1048576;       // 1,048,576
    float* rz1  = r2x  + 1048576;       // 16,384
    float* rz2x = rz1  + 16384;         // 16,384
    float* thrE = rz2x + 16384;         // 16,384
    float* A1   = thrE + 16384;         // 16,384
    float* A2   = A1   + 16384;         // 16,384

    k_gw    <<<NN / 16, 256, 0, stream>>>(h, W, a, Wh, fi, fj, E1j, E2j);
    k_rp    <<<NN / 8, 256, 0, stream>>>(fj, Wh, fs, Whp);
    k_chunks<<<HEADS * 64, 64, 0, stream>>>(fs, Whp, r1, r2x, rz1, rz2x, cs1, cs2, cz1, cz2);
    k_scan  <<<HEADS, 256, 0, stream>>>(cs1, cs2, cz1, cz2, S1, S2, Z1, Z2);
    k_q     <<<NN, 256, 0, stream>>>(fi, fs, r1, r2x, rz1, rz2x, S1, S2, Z1, Z2, out, thrE, A1, A2);

    float* attn = out + (NN * HEADS * OUT_DIM);
    k_attn  <<<NN, 256, 0, stream>>>((const float4*)E1j, (const float4*)E2j,
                                     (const float4*)thrE, (const float4*)A1,
                                     (const float4*)A2, (float4*)attn);
}

// Round 3
// 149.077 us; speedup vs baseline: 1.4076x; 1.0612x over previous
//
#include <hip/hip_runtime.h>
#include <math.h>

#define NN 4096
#define IN_DIM 256
#define HEADS 4
#define OUT_DIM 64

__device__ __forceinline__ float fexp(float x){ return __expf(x); }

// ---- K1: Wh = h@W fused with f_i/f_j/exp(f_j) tables ----
// h accessed with wave-uniform addresses -> scalar loads (no LDS staging at all).
__global__ void k_gw(const float* __restrict__ h, const float* __restrict__ W,
                     const float* __restrict__ a,
                     float* __restrict__ Wh, float* __restrict__ fi, float* __restrict__ fj,
                     float* __restrict__ E1j, float* __restrict__ E2j){
    const int i0 = blockIdx.x * 16;
    const int t  = threadIdx.x;           // output column (256 cols)
    const int hh = t >> 6, d = t & 63;    // wave == head
    float acc[16];
    #pragma unroll
    for (int r = 0; r < 16; ++r) acc[r] = 0.f;
    #pragma unroll 4
    for (int k = 0; k < IN_DIM; ++k) {
        const float w = W[k * 256 + t];   // coalesced vector load (L2)
        #pragma unroll
        for (int r = 0; r < 16; ++r)
            acc[r] += h[(i0 + r) * IN_DIM + k] * w;   // uniform addr -> s_load
    }
    const float aD = a[hh * 128 + d];
    const float aS = a[hh * 128 + 64 + d];
    #pragma unroll
    for (int r = 0; r < 16; ++r) {
        Wh[(i0 + r) * 256 + t] = acc[r];
        float p1 = acc[r] * aD, p2 = acc[r] * aS;
        #pragma unroll
        for (int off = 32; off; off >>= 1) {
            p1 += __shfl_down(p1, off);
            p2 += __shfl_down(p2, off);
        }
        if (d == 0) {
            const int n = i0 + r;
            fi[n * 4 + hh]  = p1;
            fj[n * 4 + hh]  = p2;
            E1j[n * 4 + hh] = fexp(p2);
            E2j[n * 4 + hh] = fexp(0.2f * p2);
        }
    }
}

// ---- K2: rank f_j per head (counting rank, index tiebreak) + permute Wh into sorted order ----
__global__ void k_rp(const float* __restrict__ fj, const float* __restrict__ Wh,
                     float* __restrict__ fs, float* __restrict__ Whp){
    const int j0 = blockIdx.x * 8;
    const int t = threadIdx.x;
    const int hh = t >> 6, d = t & 63;    // wave == head
    float v[8]; int cnt[8];
    #pragma unroll
    for (int r = 0; r < 8; ++r) { v[r] = fj[(j0 + r) * 4 + hh]; cnt[r] = 0; }
    for (int m = 0; m < 64; ++m) {
        const int jp = d + m * 64;
        const float x = fj[jp * 4 + hh];
        #pragma unroll
        for (int r = 0; r < 8; ++r)
            cnt[r] += (x < v[r] || (x == v[r] && jp < (j0 + r))) ? 1 : 0;
    }
    #pragma unroll
    for (int r = 0; r < 8; ++r) {
        int c = cnt[r];
        #pragma unroll
        for (int off = 32; off; off >>= 1) c += __shfl_down(c, off);
        const int rank = __shfl(c, 0);
        if (d == 0) fs[hh * NN + rank] = v[r];
        Whp[(hh * NN + rank) * 64 + d] = Wh[(j0 + r) * 256 + hh * 64 + d];
    }
}

// ---- K3: per-chunk fine suffix/prefix sums + chunk totals (4 waves, 16-deep scans) ----
__global__ void k_chunks(const float* __restrict__ fs, const float* __restrict__ Whp,
                         float* __restrict__ r1, float* __restrict__ r2x,
                         float* __restrict__ rz1, float* __restrict__ rz2x,
                         float* __restrict__ cs1, float* __restrict__ cs2,
                         float* __restrict__ cz1, float* __restrict__ cz2){
    const int b = blockIdx.x;             // 4 heads * 64 chunks
    const int H = b >> 6, c = b & 63;
    const int t = threadIdx.x;            // 256 threads = 4 waves
    const int w = t >> 6, d = t & 63;     // wave = q sub-segment of 16
    const int base = H * NN;
    const int qw = c * 64 + w * 16;
    float wv[16], e1s[16], e2s[16];
    #pragma unroll
    for (int s = 0; s < 16; ++s) {
        const int q = qw + s;
        const float f = fs[base + q];     // uniform -> s_load
        e1s[s] = fexp(f);
        e2s[s] = fexp(0.2f * f);
        wv[s]  = Whp[(size_t)(base + q) * 64 + d];
    }
    // local scans within the 16-q segment
    float p2[16], s1[16], lz1[16], lz2[16];
    float acc2 = 0.f, z2 = 0.f;
    #pragma unroll
    for (int s = 0; s < 16; ++s) {
        p2[s] = acc2; lz2[s] = z2;
        acc2 += e2s[s] * wv[s]; z2 += e2s[s];
    }
    float acc1 = 0.f, z1 = 0.f;
    #pragma unroll
    for (int s = 15; s >= 0; --s) {
        acc1 += e1s[s] * wv[s]; z1 += e1s[s];
        s1[s] = acc1; lz1[s] = z1;
    }
    // cross-wave fixup
    __shared__ float t1[4][64], t2[4][64], tz1[4], tz2[4];
    t1[w][d] = acc1; t2[w][d] = acc2;
    if (d == 0) { tz1[w] = z1; tz2[w] = z2; }
    __syncthreads();
    float off1 = 0.f, off2 = 0.f, zo1 = 0.f, zo2 = 0.f;
    #pragma unroll
    for (int w2 = 0; w2 < 4; ++w2) {
        if (w2 > w) { off1 += t1[w2][d]; zo1 += tz1[w2]; }
        if (w2 < w) { off2 += t2[w2][d]; zo2 += tz2[w2]; }
    }
    #pragma unroll
    for (int s = 0; s < 16; ++s) {
        const int q = qw + s;
        r1 [(size_t)(base + q) * 64 + d] = off1 + s1[s];
        r2x[(size_t)(base + q) * 64 + d] = off2 + p2[s];
        if (d == 0) {
            rz1 [base + q] = zo1 + lz1[s];
            rz2x[base + q] = zo2 + lz2[s];
        }
    }
    if (w == 0) {
        cs1[b * 64 + d] = off1 + acc1;            // total over all 4 waves
        if (d == 0) cz1[b] = zo1 + z1;
    }
    if (w == 3) {
        cs2[b * 64 + d] = off2 + acc2;
        if (d == 0) cz2[b] = zo2 + z2;
    }
}

// ---- K4: chunk-level scans (one block per head) ----
__global__ void k_scan(const float* __restrict__ cs1, const float* __restrict__ cs2,
                       const float* __restrict__ cz1, const float* __restrict__ cz2,
                       float* __restrict__ S1, float* __restrict__ S2,
                       float* __restrict__ Z1, float* __restrict__ Z2){
    const int H = blockIdx.x;
    const int t = threadIdx.x;
    if (t < 64) {
        const int d = t; float acc = 0.f;
        S1[(H * 65 + 64) * 64 + d] = 0.f;
        #pragma unroll 8
        for (int c = 63; c >= 0; --c) { acc += cs1[(H * 64 + c) * 64 + d]; S1[(H * 65 + c) * 64 + d] = acc; }
    } else if (t < 128) {
        const int d = t - 64; float acc = 0.f;
        S2[(H * 65 + 0) * 64 + d] = 0.f;
        #pragma unroll 8
        for (int c = 0; c < 64; ++c) { acc += cs2[(H * 64 + c) * 64 + d]; S2[(H * 65 + c + 1) * 64 + d] = acc; }
    } else if (t == 128) {
        float acc = 0.f; Z1[H * 65 + 64] = 0.f;
        for (int c = 63; c >= 0; --c) { acc += cz1[H * 64 + c]; Z1[H * 65 + c] = acc; }
    } else if (t == 129) {
        float acc = 0.f; Z2[H * 65 + 0] = 0.f;
        for (int c = 0; c < 64; ++c) { acc += cz2[H * 64 + c]; Z2[H * 65 + c + 1] = acc; }
    }
}

// ---- K5: query — ballot-based position search + O(1) loads ----
__global__ void k_q(const float* __restrict__ fi, const float* __restrict__ fs,
                    const float* __restrict__ r1, const float* __restrict__ r2x,
                    const float* __restrict__ rz1, const float* __restrict__ rz2x,
                    const float* __restrict__ S1, const float* __restrict__ S2,
                    const float* __restrict__ Z1, const float* __restrict__ Z2,
                    float* __restrict__ out, float* __restrict__ thrE,
                    float* __restrict__ A1, float* __restrict__ A2){
    const int i = blockIdx.x;
    const int t = threadIdx.x;
    const int hh = t >> 6, d = t & 63;    // wave == head
    const int base = hh * NN;
    const float s = fi[i * 4 + hh];
    const float thr = -s;
    const unsigned long long m1 = __ballot(fs[base + d * 64] < thr);
    const int k1 = __popcll(m1);
    int p = 0;
    if (k1 > 0) {
        const int cc = k1 - 1;
        const unsigned long long m2 = __ballot(fs[base + cc * 64 + d] < thr);
        p = cc * 64 + __popcll(m2);
    }
    float a1, a2, z1, z2;
    if (p == NN) {
        a1 = 0.f; z1 = 0.f;
        a2 = S2[(hh * 65 + 64) * 64 + d]; z2 = Z2[hh * 65 + 64];
    } else {
        const int c = p >> 6;
        a1 = r1 [(base + p) * 64 + d] + S1[(hh * 65 + c + 1) * 64 + d];
        z1 = rz1[base + p]            + Z1[hh * 65 + c + 1];
        a2 = r2x[(base + p) * 64 + d] + S2[(hh * 65 + c) * 64 + d];
        z2 = rz2x[base + p]           + Z2[hh * 65 + c];
    }
    const float E1 = fexp(s), E2 = fexp(0.2f * s);
    const float iz = 1.f / (E1 * z1 + E2 * z2);
    out[i * 256 + t] = (E1 * a1 + E2 * a2) * iz;
    if (d == 0) {
        thrE[i * 4 + hh] = fexp(thr);
        A1[i * 4 + hh]   = E1 * iz;
        A2[i * 4 + hh]   = E2 * iz;
    }
}

// ---- K6: attn write — no transcendentals, 2 table loads + select per quad ----
__global__ void k_attn(const float4* __restrict__ E1j4, const float4* __restrict__ E2j4,
                       const float4* __restrict__ thrE4, const float4* __restrict__ A14,
                       const float4* __restrict__ A24, float4* __restrict__ attn){
    const int i = blockIdx.x;
    const float4 th = thrE4[i];
    const float4 a1 = A14[i];
    const float4 a2 = A24[i];
    float4* __restrict__ row = attn + (size_t)i * NN;
    const int t = threadIdx.x;
    #pragma unroll
    for (int it = 0; it < 16; ++it) {
        const int j = it * 256 + t;
        const float4 e1 = E1j4[j];
        const float4 e2 = E2j4[j];
        float4 o;
        o.x = (e1.x >= th.x) ? a1.x * e1.x : a2.x * e2.x;
        o.y = (e1.y >= th.y) ? a1.y * e1.y : a2.y * e2.y;
        o.z = (e1.z >= th.z) ? a1.z * e1.z : a2.z * e2.z;
        o.w = (e1.w >= th.w) ? a1.w * e1.w : a2.w * e2.w;
        row[j] = o;
    }
}

extern "C" void kernel_launch(void* const* d_in, const int* in_sizes, int n_in,
                              void* d_out, int out_size, void* d_ws, size_t ws_size,
                              hipStream_t stream) {
    const float* h = (const float*)d_in[0];
    const float* W = (const float*)d_in[1];
    const float* a = (const float*)d_in[2];
    float* out = (float*)d_out;
    float* ws  = (float*)d_ws;

    float* Wh   = ws;                   // 1,048,576
    float* Whp  = Wh   + 1048576;       // 1,048,576
    float* fi   = Whp  + 1048576;       // 16,384
    float* fj   = fi   + 16384;         // 16,384
    float* E1j  = fj   + 16384;         // 16,384
    float* E2j  = E1j  + 16384;         // 16,384
    float* fs   = E2j  + 16384;         // 16,384
    float* cs1  = fs   + 16384;         // 16,384
    float* cs2  = cs1  + 16384;         // 16,384
    float* cz1  = cs2  + 16384;         // 256
    float* cz2  = cz1  + 256;           // 256
    float* S1   = cz2  + 256;           // 16,640
    float* S2   = S1   + 16640;         // 16,640
    float* Z1   = S2   + 16640;         // 260
    float* Z2   = Z1   + 260;           // 260
    float* r1   = Z2   + 260;           // 1,048,576
    float* r2x  = r1   + 1048576;       // 1,048,576
    float* rz1  = r2x  + 1048576;       // 16,384
    float* rz2x = rz1  + 16384;         // 16,384
    float* thrE = rz2x + 16384;         // 16,384
    float* A1   = thrE + 16384;         // 16,384
    float* A2   = A1   + 16384;         // 16,384

    k_gw    <<<NN / 16, 256, 0, stream>>>(h, W, a, Wh, fi, fj, E1j, E2j);
    k_rp    <<<NN / 8, 256, 0, stream>>>(fj, Wh, fs, Whp);
    k_chunks<<<HEADS * 64, 256, 0, stream>>>(fs, Whp, r1, r2x, rz1, rz2x, cs1, cs2, cz1, cz2);
    k_scan  <<<HEADS, 256, 0, stream>>>(cs1, cs2, cz1, cz2, S1, S2, Z1, Z2);
    k_q     <<<NN, 256, 0, stream>>>(fi, fs, r1, r2x, rz1, rz2x, S1, S2, Z1, Z2, out, thrE, A1, A2);

    float* attn = out + (NN * HEADS * OUT_DIM);
    k_attn  <<<NN, 256, 0, stream>>>((const float4*)E1j, (const float4*)E2j,
                                     (const float4*)thrE, (const float4*)A1,
                                     (const float4*)A2, (float4*)attn);
}

// Round 4
// 132.016 us; speedup vs baseline: 1.5895x; 1.1292x over previous
//
#include <hip/hip_runtime.h>
#include <math.h>

#define NN 4096
#define IN_DIM 256
#define HEADS 4
#define OUT_DIM 64

__device__ __forceinline__ float fexp(float x){ return __expf(x); }

// ---- K1: Wh = h@W fused with f_i/f_j/exp(f_j) tables ----
// 512 blocks (2/CU), 8 rows x 256 cols each. h tile in LDS, read as b128 broadcast.
__global__ void k_gw(const float* __restrict__ h, const float* __restrict__ W,
                     const float* __restrict__ a,
                     float* __restrict__ Wh, float* __restrict__ fi, float* __restrict__ fjT,
                     float* __restrict__ E1j, float* __restrict__ E2j){
    __shared__ float4 hs4[8][64];         // 8 rows x 256 k  (8 KB)
    const int i0 = blockIdx.x * 8;
    const int t  = threadIdx.x;           // output column (256 cols)
    const int hh = t >> 6, d = t & 63;    // wave == head
    {
        const float4* h4 = (const float4*)h;
        hs4[t >> 6][t & 63]         = h4[(i0 + (t >> 6)) * 64 + (t & 63)];
        hs4[(t >> 6) + 4][t & 63]   = h4[(i0 + (t >> 6) + 4) * 64 + (t & 63)];
    }
    __syncthreads();
    float acc[8];
    #pragma unroll
    for (int r = 0; r < 8; ++r) acc[r] = 0.f;
    #pragma unroll 4
    for (int kq = 0; kq < 64; ++kq) {
        const int k = kq * 4;
        const float w0 = W[(k + 0) * 256 + t];
        const float w1 = W[(k + 1) * 256 + t];
        const float w2 = W[(k + 2) * 256 + t];
        const float w3 = W[(k + 3) * 256 + t];
        #pragma unroll
        for (int r = 0; r < 8; ++r) {
            const float4 hv = hs4[r][kq];     // wave-uniform -> LDS broadcast
            acc[r] = fmaf(hv.x, w0, acc[r]);
            acc[r] = fmaf(hv.y, w1, acc[r]);
            acc[r] = fmaf(hv.z, w2, acc[r]);
            acc[r] = fmaf(hv.w, w3, acc[r]);
        }
    }
    const float aD = a[hh * 128 + d];
    const float aS = a[hh * 128 + 64 + d];
    #pragma unroll
    for (int r = 0; r < 8; ++r) {
        Wh[(i0 + r) * 256 + t] = acc[r];
        float p1 = acc[r] * aD, p2 = acc[r] * aS;
        #pragma unroll
        for (int off = 32; off; off >>= 1) {
            p1 += __shfl_down(p1, off);
            p2 += __shfl_down(p2, off);
        }
        if (d == 0) {
            const int n = i0 + r;
            fi[n * 4 + hh]   = p1;
            fjT[hh * NN + n] = p2;
            E1j[n * 4 + hh]  = fexp(p2);
            E2j[n * 4 + hh]  = fexp(0.2f * p2);
        }
    }
}

// ---- K2: rank f_j per head (counting rank, index tiebreak) + permute Wh into sorted order ----
__global__ void k_rp(const float* __restrict__ fjT, const float* __restrict__ Wh,
                     float* __restrict__ fs, float* __restrict__ Whp){
    const int j0 = blockIdx.x * 8;
    const int t = threadIdx.x;
    const int hh = t >> 6, d = t & 63;    // wave == head
    const int base = hh * NN;
    float v[8]; int cnt[8];
    #pragma unroll
    for (int r = 0; r < 8; ++r) { v[r] = fjT[base + j0 + r]; cnt[r] = 0; }
    #pragma unroll 4
    for (int m = 0; m < 64; ++m) {
        const int jp = d + m * 64;
        const float x = fjT[base + jp];   // coalesced 256B per wave
        #pragma unroll
        for (int r = 0; r < 8; ++r)
            cnt[r] += (x < v[r] || (x == v[r] && jp < (j0 + r))) ? 1 : 0;
    }
    #pragma unroll
    for (int r = 0; r < 8; ++r) {
        int c = cnt[r];
        #pragma unroll
        for (int off = 32; off; off >>= 1) c += __shfl_down(c, off);
        const int rank = __shfl(c, 0);
        if (d == 0) fs[base + rank] = v[r];
        Whp[(size_t)(base + rank) * 64 + d] = Wh[(j0 + r) * 256 + hh * 64 + d];
    }
}

// ---- K3: per-chunk fine suffix/prefix sums + chunk totals (4 waves, 16-deep scans) ----
__global__ void k_chunks(const float* __restrict__ fs, const float* __restrict__ Whp,
                         float* __restrict__ r1, float* __restrict__ r2x,
                         float* __restrict__ rz1, float* __restrict__ rz2x,
                         float* __restrict__ cs1, float* __restrict__ cs2,
                         float* __restrict__ cz1, float* __restrict__ cz2){
    const int b = blockIdx.x;             // 4 heads * 64 chunks
    const int H = b >> 6, c = b & 63;
    const int t = threadIdx.x;            // 256 threads = 4 waves
    const int w = t >> 6, d = t & 63;     // wave = q sub-segment of 16
    const int base = H * NN;
    const int qw = c * 64 + w * 16;
    float wv[16], e1s[16], e2s[16];
    #pragma unroll
    for (int s = 0; s < 16; ++s) {
        const int q = qw + s;
        const float f = fs[base + q];
        e1s[s] = fexp(f);
        e2s[s] = fexp(0.2f * f);
        wv[s]  = Whp[(size_t)(base + q) * 64 + d];
    }
    float p2[16], s1[16], lz1[16], lz2[16];
    float acc2 = 0.f, z2 = 0.f;
    #pragma unroll
    for (int s = 0; s < 16; ++s) {
        p2[s] = acc2; lz2[s] = z2;
        acc2 += e2s[s] * wv[s]; z2 += e2s[s];
    }
    float acc1 = 0.f, z1 = 0.f;
    #pragma unroll
    for (int s = 15; s >= 0; --s) {
        acc1 += e1s[s] * wv[s]; z1 += e1s[s];
        s1[s] = acc1; lz1[s] = z1;
    }
    __shared__ float t1[4][64], t2[4][64], tz1[4], tz2[4];
    t1[w][d] = acc1; t2[w][d] = acc2;
    if (d == 0) { tz1[w] = z1; tz2[w] = z2; }
    __syncthreads();
    float off1 = 0.f, off2 = 0.f, zo1 = 0.f, zo2 = 0.f;
    #pragma unroll
    for (int w2 = 0; w2 < 4; ++w2) {
        if (w2 > w) { off1 += t1[w2][d]; zo1 += tz1[w2]; }
        if (w2 < w) { off2 += t2[w2][d]; zo2 += tz2[w2]; }
    }
    #pragma unroll
    for (int s = 0; s < 16; ++s) {
        const int q = qw + s;
        r1 [(size_t)(base + q) * 64 + d] = off1 + s1[s];
        r2x[(size_t)(base + q) * 64 + d] = off2 + p2[s];
        if (d == 0) {
            rz1 [base + q] = zo1 + lz1[s];
            rz2x[base + q] = zo2 + lz2[s];
        }
    }
    if (w == 0) {
        cs1[b * 64 + d] = off1 + acc1;
        if (d == 0) cz1[b] = zo1 + z1;
    }
    if (w == 3) {
        cs2[b * 64 + d] = off2 + acc2;
        if (d == 0) cz2[b] = zo2 + z2;
    }
}

// ---- K4: chunk-level scans (one block per head) ----
__global__ void k_scan(const float* __restrict__ cs1, const float* __restrict__ cs2,
                       const float* __restrict__ cz1, const float* __restrict__ cz2,
                       float* __restrict__ S1, float* __restrict__ S2,
                       float* __restrict__ Z1, float* __restrict__ Z2){
    const int H = blockIdx.x;
    const int t = threadIdx.x;
    if (t < 64) {
        const int d = t; float acc = 0.f;
        S1[(H * 65 + 64) * 64 + d] = 0.f;
        #pragma unroll 8
        for (int c = 63; c >= 0; --c) { acc += cs1[(H * 64 + c) * 64 + d]; S1[(H * 65 + c) * 64 + d] = acc; }
    } else if (t < 128) {
        const int d = t - 64; float acc = 0.f;
        S2[(H * 65 + 0) * 64 + d] = 0.f;
        #pragma unroll 8
        for (int c = 0; c < 64; ++c) { acc += cs2[(H * 64 + c) * 64 + d]; S2[(H * 65 + c + 1) * 64 + d] = acc; }
    } else if (t == 128) {
        float acc = 0.f; Z1[H * 65 + 64] = 0.f;
        for (int c = 63; c >= 0; --c) { acc += cz1[H * 64 + c]; Z1[H * 65 + c] = acc; }
    } else if (t == 129) {
        float acc = 0.f; Z2[H * 65 + 0] = 0.f;
        for (int c = 0; c < 64; ++c) { acc += cz2[H * 64 + c]; Z2[H * 65 + c + 1] = acc; }
    }
}

// ---- K5: query — ballot-based position search + O(1) loads ----
__global__ void k_q(const float* __restrict__ fi, const float* __restrict__ fs,
                    const float* __restrict__ r1, const float* __restrict__ r2x,
                    const float* __restrict__ rz1, const float* __restrict__ rz2x,
                    const float* __restrict__ S1, const float* __restrict__ S2,
                    const float* __restrict__ Z1, const float* __restrict__ Z2,
                    float* __restrict__ out, float* __restrict__ thrE,
                    float* __restrict__ A1, float* __restrict__ A2){
    const int i = blockIdx.x;
    const int t = threadIdx.x;
    const int hh = t >> 6, d = t & 63;    // wave == head
    const int base = hh * NN;
    const float s = fi[i * 4 + hh];
    const float thr = -s;
    const unsigned long long m1 = __ballot(fs[base + d * 64] < thr);
    const int k1 = __popcll(m1);
    int p = 0;
    if (k1 > 0) {
        const int cc = k1 - 1;
        const unsigned long long m2 = __ballot(fs[base + cc * 64 + d] < thr);
        p = cc * 64 + __popcll(m2);
    }
    float a1, a2, z1, z2;
    if (p == NN) {
        a1 = 0.f; z1 = 0.f;
        a2 = S2[(hh * 65 + 64) * 64 + d]; z2 = Z2[hh * 65 + 64];
    } else {
        const int c = p >> 6;
        a1 = r1 [(size_t)(base + p) * 64 + d] + S1[(hh * 65 + c + 1) * 64 + d];
        z1 = rz1[base + p]                    + Z1[hh * 65 + c + 1];
        a2 = r2x[(size_t)(base + p) * 64 + d] + S2[(hh * 65 + c) * 64 + d];
        z2 = rz2x[base + p]                   + Z2[hh * 65 + c];
    }
    const float E1 = fexp(s), E2 = fexp(0.2f * s);
    const float iz = 1.f / (E1 * z1 + E2 * z2);
    out[i * 256 + t] = (E1 * a1 + E2 * a2) * iz;
    if (d == 0) {
        thrE[i * 4 + hh] = fexp(thr);
        A1[i * 4 + hh]   = E1 * iz;
        A2[i * 4 + hh]   = E2 * iz;
    }
}

// ---- K6: attn write — no transcendentals, 2 table loads + select per quad ----
__global__ void k_attn(const float4* __restrict__ E1j4, const float4* __restrict__ E2j4,
                       const float4* __restrict__ thrE4, const float4* __restrict__ A14,
                       const float4* __restrict__ A24, float4* __restrict__ attn){
    const int i = blockIdx.x;
    const float4 th = thrE4[i];
    const float4 a1 = A14[i];
    const float4 a2 = A24[i];
    float4* __restrict__ row = attn + (size_t)i * NN;
    const int t = threadIdx.x;
    #pragma unroll
    for (int it = 0; it < 16; ++it) {
        const int j = it * 256 + t;
        const float4 e1 = E1j4[j];
        const float4 e2 = E2j4[j];
        float4 o;
        o.x = (e1.x >= th.x) ? a1.x * e1.x : a2.x * e2.x;
        o.y = (e1.y >= th.y) ? a1.y * e1.y : a2.y * e2.y;
        o.z = (e1.z >= th.z) ? a1.z * e1.z : a2.z * e2.z;
        o.w = (e1.w >= th.w) ? a1.w * e1.w : a2.w * e2.w;
        row[j] = o;
    }
}

extern "C" void kernel_launch(void* const* d_in, const int* in_sizes, int n_in,
                              void* d_out, int out_size, void* d_ws, size_t ws_size,
                              hipStream_t stream) {
    const float* h = (const float*)d_in[0];
    const float* W = (const float*)d_in[1];
    const float* a = (const float*)d_in[2];
    float* out = (float*)d_out;
    float* ws  = (float*)d_ws;

    float* Wh   = ws;                   // 1,048,576
    float* Whp  = Wh   + 1048576;       // 1,048,576
    float* fi   = Whp  + 1048576;       // 16,384
    float* fjT  = fi   + 16384;         // 16,384
    float* E1j  = fjT  + 16384;         // 16,384
    float* E2j  = E1j  + 16384;         // 16,384
    float* fs   = E2j  + 16384;         // 16,384
    float* cs1  = fs   + 16384;         // 16,384
    float* cs2  = cs1  + 16384;         // 16,384
    float* cz1  = cs2  + 16384;         // 256
    float* cz2  = cz1  + 256;           // 256
    float* S1   = cz2  + 256;           // 16,640
    float* S2   = S1   + 16640;         // 16,640
    float* Z1   = S2   + 16640;         // 260
    float* Z2   = Z1   + 260;           // 260
    float* r1   = Z2   + 260;           // 1,048,576
    float* r2x  = r1   + 1048576;       // 1,048,576
    float* rz1  = r2x  + 1048576;       // 16,384
    float* rz2x = rz1  + 16384;         // 16,384
    float* thrE = rz2x + 16384;         // 16,384
    float* A1   = thrE + 16384;         // 16,384
    float* A2   = A1   + 16384;         // 16,384

    k_gw    <<<NN / 8, 256, 0, stream>>>(h, W, a, Wh, fi, fjT, E1j, E2j);
    k_rp    <<<NN / 8, 256, 0, stream>>>(fjT, Wh, fs, Whp);
    k_chunks<<<HEADS * 64, 256, 0, stream>>>(fs, Whp, r1, r2x, rz1, rz2x, cs1, cs2, cz1, cz2);
    k_scan  <<<HEADS, 256, 0, stream>>>(cs1, cs2, cz1, cz2, S1, S2, Z1, Z2);
    k_q     <<<NN, 256, 0, stream>>>(fi, fs, r1, r2x, rz1, rz2x, S1, S2, Z1, Z2, out, thrE, A1, A2);

    float* attn = out + (NN * HEADS * OUT_DIM);
    k_attn  <<<NN, 256, 0, stream>>>((const float4*)E1j, (const float4*)E2j,
                                     (const float4*)thrE, (const float4*)A1,
                                     (const float4*)A2, (float4*)attn);
}